// Round 5
// baseline (353.022 us; speedup 1.0000x reference)
//
#include <hip/hip_runtime.h>

#define N_SAMPLES 32768
#define N_EMBED   10000
#define KPAD      10240        // padded cluster count
#define HLEN      5120         // clusters per half
#define ITERS     160          // HLEN / 32
#define DIM       128
#define OUT_ELEMS 4194304      // 4*8*32*32*128
#define IDX_OFF   4194304
#define LOSS_OFF  4227072

// workspace byte offsets
#define WS_CNH      0u          // f32[10240] = -||e||^2/2 (pad: -1.5e38)
#define WS_NEWSIZE  65536u      // f32[10000] (counts then new_size)
#define WS_SUMS     131072u     // f32[1280000] (sums then new_mean)
#define WS_NSAMPLE  5251072u    // f64
#define WS_LOSS     5251080u    // f64
#define WS_PACKED   5251088u    // u64[32768]
#define WS_EHI      6291456u    // f16[10240*128]
#define WS_ELO      8912896u    // f16[10240*128]

// LDS tile geometry: 32 cluster rows x 128 f16, padded row = 272B (256+16)
#define ROWB   272
#define LO_OFF 8704            // 32*272
#define BUFSZ  17408           // hi + lo

typedef _Float16 f16;
typedef __attribute__((ext_vector_type(8)))  _Float16 f16x8;
typedef __attribute__((ext_vector_type(16))) float    f32x16;

__device__ inline unsigned long long shflx64(unsigned long long v, int m) {
    int lo = __shfl_xor((int)(unsigned int)(v & 0xffffffffull), m, 64);
    int hi = __shfl_xor((int)(unsigned int)(v >> 32), m, 64);
    return ((unsigned long long)(unsigned int)hi << 32) | (unsigned int)lo;
}

// ---------------- split E + negated-half norms (padded to 10240) ----------------
__global__ __launch_bounds__(128) void k_prepe(const float* __restrict__ cm,
                                               f16* __restrict__ ehi,
                                               f16* __restrict__ elo,
                                               float* __restrict__ cnh) {
    __shared__ float pw[2];
    int c = blockIdx.x, d = threadIdx.x;
    float e = (c < N_EMBED) ? cm[(size_t)c * DIM + d] : 0.f;
    f16 h = (f16)e;
    ehi[(size_t)c * DIM + d] = h;
    elo[(size_t)c * DIM + d] = (f16)(e - (float)h);
    float s = e * e;
    #pragma unroll
    for (int off = 32; off; off >>= 1) s += __shfl_down(s, off, 64);
    if ((threadIdx.x & 63) == 0) pw[threadIdx.x >> 6] = s;
    __syncthreads();
    if (threadIdx.x == 0)
        cnh[c] = (c < N_EMBED) ? -0.5f * (pw[0] + pw[1]) : -1.5e38f;
}

// ---------------- MFMA argmin: 32x32x16, samples=A (regs), clusters=B (LDS) ----------------
// 512 blocks = 256 sample-groups x 2 cluster-halves (half = blockIdx&1, so even/odd
// XCDs each keep one 2.6MB half L2-resident). Block: 4 waves x 32 samples; 32-cluster
// tiles staged in padded LDS (double-buffered), shared by all 4 waves.
// D[row][col]: row = sample (reg-indexed), col = lane&31 = cluster-in-tile.
// acc init = cnh[cluster] (per-lane scalar) -> per-reg exact running argMAX.
__global__ __launch_bounds__(256, 2) void k_argmin(const float* __restrict__ inp,
                                                   const f16* __restrict__ ehi,
                                                   const f16* __restrict__ elo,
                                                   const float* __restrict__ cnh,
                                                   unsigned long long* __restrict__ packed) {
    __shared__ __align__(16) char lds[2 * BUFSZ];
    const int tid = threadIdx.x;
    const int wave = tid >> 6, lane = tid & 63;
    const int l31 = lane & 31, h = lane >> 5;
    const int g = blockIdx.x >> 1;
    const int kbase = (blockIdx.x & 1) * HLEN;
    const int sbase = g * 128 + wave * 32;

    // ---- A-frags: in-register f16 hi/lo split of this lane's sample row ----
    // row = l31 -> sample sbase+l31; k = ks*16 + h*8 + e
    f16x8 ah[8], al[8];
    {
        const float* xr = inp + (size_t)(sbase + l31) * DIM + h * 8;
        #pragma unroll
        for (int ks = 0; ks < 8; ++ks) {
            float4 u0 = *(const float4*)(xr + ks * 16);
            float4 u1 = *(const float4*)(xr + ks * 16 + 4);
            float v[8] = {u0.x, u0.y, u0.z, u0.w, u1.x, u1.y, u1.z, u1.w};
            f16x8 hv, lv;
            #pragma unroll
            for (int e = 0; e < 8; ++e) {
                f16 hh = (f16)v[e];
                hv[e] = hh;
                lv[e] = (f16)(v[e] - (float)hh);
            }
            ah[ks] = hv; al[ks] = lv;
        }
    }

    // B-frag LDS read base: cluster row = l31, byte = l31*ROWB + h*16 + ks*32
    const int rb = l31 * ROWB + h * 16;
    // staging: thread stages 2 hi + 2 lo 16B chunks of next tile
    const int strow = tid >> 3;            // 0..31
    const int scp = (tid & 7) * 2;         // chunk pair 0,2,..,14
    const int wadr = strow * ROWB + scp * 16;

    float best[16];
    int bi[16];
    #pragma unroll
    for (int r = 0; r < 16; ++r) { best[r] = -3.4e38f; bi[r] = 0; }

    // ---- prologue: stage tile 0, load its cn ----
    float cn_cur;
    {
        const size_t gs = (size_t)(kbase + strow) * DIM + scp * 8;
        f16x8 sh0 = *(const f16x8*)(ehi + gs);
        f16x8 sh1 = *(const f16x8*)(ehi + gs + 8);
        f16x8 sl0 = *(const f16x8*)(elo + gs);
        f16x8 sl1 = *(const f16x8*)(elo + gs + 8);
        cn_cur = cnh[kbase + l31];
        *(f16x8*)(lds + wadr)               = sh0;
        *(f16x8*)(lds + wadr + 16)          = sh1;
        *(f16x8*)(lds + LO_OFF + wadr)      = sl0;
        *(f16x8*)(lds + LO_OFF + wadr + 16) = sl1;
        __syncthreads();
    }

    int cur = 0;
    for (int it = 0; it < ITERS; ++it) {
        const int c0 = kbase + it * 32;
        // issue next tile's global loads early (hide under MFMA)
        f16x8 sh0, sh1, sl0, sl1; float cn_nx = 0.f;
        if (it < ITERS - 1) {
            const size_t gs = (size_t)(c0 + 32 + strow) * DIM + scp * 8;
            sh0 = *(const f16x8*)(ehi + gs);
            sh1 = *(const f16x8*)(ehi + gs + 8);
            sl0 = *(const f16x8*)(elo + gs);
            sl1 = *(const f16x8*)(elo + gs + 8);
            cn_nx = cnh[c0 + 32 + l31];
        }

        const char* lr = lds + cur * BUFSZ + rb;
        f32x16 acc;
        #pragma unroll
        for (int r = 0; r < 16; ++r) acc[r] = cn_cur;
        #pragma unroll
        for (int ks = 0; ks < 8; ++ks) {
            f16x8 bh = *(const f16x8*)(lr + ks * 32);
            f16x8 bl = *(const f16x8*)(lr + LO_OFF + ks * 32);
            acc = __builtin_amdgcn_mfma_f32_32x32x16_f16(ah[ks], bh, acc, 0, 0, 0);
            acc = __builtin_amdgcn_mfma_f32_32x32x16_f16(ah[ks], bl, acc, 0, 0, 0);
            acc = __builtin_amdgcn_mfma_f32_32x32x16_f16(al[ks], bh, acc, 0, 0, 0);
        }

        // exact per-reg running argMAX (candidate cluster = c0 + l31, wave-uniform c0)
        const int cv = c0 + l31;
        #pragma unroll
        for (int r = 0; r < 16; ++r) {
            bool gt = acc[r] > best[r];
            best[r] = gt ? acc[r] : best[r];
            bi[r]   = gt ? cv : bi[r];
        }

        if (it < ITERS - 1) {
            char* lw = lds + (cur ^ 1) * BUFSZ;
            *(f16x8*)(lw + wadr)               = sh0;
            *(f16x8*)(lw + wadr + 16)          = sh1;
            *(f16x8*)(lw + LO_OFF + wadr)      = sl0;
            *(f16x8*)(lw + LO_OFF + wadr + 16) = sl1;
            __syncthreads();
            cn_cur = cn_nx;
            cur ^= 1;
        }
    }

    // ---- epilogue: per-reg reduce across the 32 cluster-lanes of this half ----
    // reg r holds sample row (r&3) + 8*(r>>2) + 4*h (same row for all 32 lanes of a half)
    #pragma unroll
    for (int r = 0; r < 16; ++r) {
        unsigned int b = __float_as_uint(best[r]);
        unsigned int t = (b & 0x80000000u) ? ~b : (b | 0x80000000u); // monotone inc
        unsigned long long p = ((unsigned long long)(~t) << 32) | (unsigned int)bi[r];
        #pragma unroll
        for (int m = 1; m < 32; m <<= 1) {
            unsigned long long o = shflx64(p, m);
            p = p < o ? p : o;
        }
        if (l31 == r) {
            const int srow = (r & 3) + 8 * (r >> 2) + 4 * h;
            atomicMin(&packed[sbase + srow], p);
        }
    }
}

// ---------------- scatter: counts + sums + idx output ----------------
__global__ __launch_bounds__(256) void k_scatter(const float* __restrict__ inp,
                                                 const unsigned long long* __restrict__ packed,
                                                 float* __restrict__ sums,
                                                 float* __restrict__ counts,
                                                 float* __restrict__ idxf) {
    int j = blockIdx.x * 256 + threadIdx.x;   // < 4194304
    int i = j >> 7, d = j & 127;
    int k = (int)(unsigned int)(packed[i] & 0xFFFFFFFFull);
    atomicAdd(&sums[(size_t)k * DIM + d], inp[j]);
    if (d == 0) {
        atomicAdd(&counts[k], 1.0f);
        idxf[i] = (float)k;
    }
}

// ---------------- new_size + n_sample ----------------
__global__ __launch_bounds__(256) void k_newsize(const float* __restrict__ csize,
                                                 float* __restrict__ newsize,
                                                 double* __restrict__ nsample) {
    int k = blockIdx.x * 256 + threadIdx.x;
    float ns = 0.f;
    if (k < N_EMBED) {
        ns = csize[k] * 0.99f + newsize[k] * 0.01f;
        newsize[k] = ns;
    }
    float s = ns;
    #pragma unroll
    for (int off = 32; off; off >>= 1) s += __shfl_down(s, off, 64);
    if ((threadIdx.x & 63) == 0) atomicAdd(nsample, (double)s);
}

// ---------------- new_mean (in place over sums) ----------------
__global__ __launch_bounds__(256) void k_newmean(const float* __restrict__ csum,
                                                 float* __restrict__ sums,
                                                 const float* __restrict__ newsize,
                                                 const double* __restrict__ nsample) {
    int j = blockIdx.x * 256 + threadIdx.x;   // < 1280000
    float nsmp = (float)(*nsample);
    int k = j >> 7;
    float sm = (newsize[k] + 1e-5f) * nsmp / (nsmp + 0.1f);
    sums[j] = (csum[j] * 0.99f + sums[j] * 0.01f) / sm;
}

// ---------------- gather + output + two-stage loss ----------------
__global__ __launch_bounds__(256) void k_gather(const float* __restrict__ inp,
                                                const float* __restrict__ nm,
                                                const unsigned long long* __restrict__ packed,
                                                float* __restrict__ out,
                                                double* __restrict__ lossacc) {
    __shared__ double pw[4];
    int t0 = blockIdx.x * 256 + threadIdx.x;    // grid 512 -> t0 < 131072
    double de = 0.0;
    #pragma unroll
    for (int it = 0; it < 8; ++it) {
        int j4 = t0 + it * 131072;              // float4 index < 1048576
        int i = j4 >> 5, d4 = j4 & 31;
        int k = (int)(unsigned int)(packed[i] & 0xFFFFFFFFull);
        float4 x = ((const float4*)inp)[j4];
        float4 qv = ((const float4*)(nm + (size_t)k * DIM))[d4];
        float4 o;
        o.x = x.x + (qv.x - x.x); o.y = x.y + (qv.y - x.y);
        o.z = x.z + (qv.z - x.z); o.w = x.w + (qv.w - x.w);
        ((float4*)out)[j4] = o;
        float dx = x.x - qv.x, dy = x.y - qv.y, dz = x.z - qv.z, dw = x.w - qv.w;
        de += (double)(dx * dx + dy * dy + dz * dz + dw * dw);
    }
    #pragma unroll
    for (int off = 32; off; off >>= 1) de += __shfl_down(de, off, 64);
    if ((threadIdx.x & 63) == 0) pw[threadIdx.x >> 6] = de;
    __syncthreads();
    if (threadIdx.x == 0)
        atomicAdd(lossacc, pw[0] + pw[1] + pw[2] + pw[3]);
}

__global__ void k_lossfinal(const double* __restrict__ lossacc,
                            float* __restrict__ lossout) {
    *lossout = 0.25f * (float)(*lossacc / (double)OUT_ELEMS);
}

extern "C" void kernel_launch(void* const* d_in, const int* in_sizes, int n_in,
                              void* d_out, int out_size, void* d_ws, size_t ws_size,
                              hipStream_t stream) {
    const float* inp   = (const float*)d_in[0];
    const float* cmean = (const float*)d_in[1];
    const float* csize = (const float*)d_in[2];
    const float* csum  = (const float*)d_in[3];
    float* out = (float*)d_out;
    char*  ws  = (char*)d_ws;

    float*  cnh     = (float*)(ws + WS_CNH);
    float*  newsize = (float*)(ws + WS_NEWSIZE);
    float*  sums    = (float*)(ws + WS_SUMS);
    double* nsample = (double*)(ws + WS_NSAMPLE);
    double* lossacc = (double*)(ws + WS_LOSS);
    unsigned long long* packed = (unsigned long long*)(ws + WS_PACKED);
    f16* ehi = (f16*)(ws + WS_EHI);
    f16* elo = (f16*)(ws + WS_ELO);
    float* idxf = out + IDX_OFF;

    // zero counts/sums/nsample/loss; fill packed with 0xFF (u64 max)
    hipMemsetAsync(ws + WS_NEWSIZE, 0, (WS_LOSS + 8) - WS_NEWSIZE, stream);
    hipMemsetAsync(ws + WS_PACKED, 0xFF, (size_t)N_SAMPLES * 8, stream);

    k_prepe  <<<KPAD, 128, 0, stream>>>(cmean, ehi, elo, cnh);
    k_argmin <<<512, 256, 0, stream>>>(inp, ehi, elo, cnh, packed);
    k_scatter<<<OUT_ELEMS / 256, 256, 0, stream>>>(inp, packed, sums, newsize, idxf);
    k_newsize<<<(N_EMBED + 255) / 256, 256, 0, stream>>>(csize, newsize, nsample);
    k_newmean<<<(N_EMBED * DIM) / 256, 256, 0, stream>>>(csum, sums, newsize, nsample);
    k_gather <<<512, 256, 0, stream>>>(inp, sums, packed, out, lossacc);
    k_lossfinal<<<1, 1, 0, stream>>>(lossacc, out + LOSS_OFF);
}